// Round 6
// baseline (250.146 us; speedup 1.0000x reference)
//
#include <hip/hip_runtime.h>
#include <cstdint>

#define D 128
#define T 64
#define B 512
#define EPSF 1e-5f

// wave-uniform lane broadcast via v_readlane
__device__ __forceinline__ float lane_bcast(float x, int l) {
    return __int_as_float(__builtin_amdgcn_readlane(__float_as_int(x), l));
}

// ---------------------------------------------------------------------------
// Quad layout: Q[j2][i2] = (v[i2][2j2], v[i2][2j2+1], v[i2+64][2j2], v[i2+64][2j2+1])
// at float4-index j2*64 + (i2 ^ (j2&7)).   (note: (32+j2)&7 == j2&7)
//  - uniform-j2 reads (matvec/probe/sweep): contiguous 1024B row -> conflict-free
//  - per-lane j2 reads (judge): 8 lanes per 4-bank group -> structural minimum
// ---------------------------------------------------------------------------
__global__ __launch_bounds__(64) void prep_kernel(const float* __restrict__ W,
                                                  const float* __restrict__ b,
                                                  float* __restrict__ csw,
                                                  float* __restrict__ vd,
                                                  float* __restrict__ absb) {
    const int i = blockIdx.x;
    const int l = threadIdx.x;
    float w0 = W[i * D + l];
    float w1 = W[i * D + l + 64];
    float p = w0 * w0 + w1 * w1;
#pragma unroll
    for (int off = 32; off; off >>= 1) p += __shfl_xor(p, off);
    float norm = sqrtf(p);
    float scale = norm > 1e-12f ? norm : 1e-12f;
    float v0 = w0 / scale;   // v[i][l]
    float v1 = w1 / scale;   // v[i][l+64]
    const int i2 = i & 63, half = i >> 6;
    const int j2 = l >> 1, par = l & 1;
    const int sub = par + 2 * half;
    csw[4 * (j2 * 64 + (i2 ^ (j2 & 7))) + sub] = v0;          // k = l
    csw[4 * ((32 + j2) * 64 + (i2 ^ (j2 & 7))) + sub] = v1;   // k = l + 64
    if (i < 64) { if (l == i) vd[i] = v0; }
    else        { if (l == i - 64) vd[i] = v1; }
    if (i == 0) {
        absb[l] = fabsf(b[l]);
        absb[l + 64] = fabsf(b[l + 64]);
    }
}

// uniform-j column fetch from quad layout: (v[i2][j], v[i2+64][j])
__device__ __forceinline__ float2 colq(const float* csh, int j, int i2) {
    int j2 = j >> 1;
    const float4 q = *(const float4*)(csh + 4 * (j2 * 64 + (i2 ^ (j2 & 7))));
    return (j & 1) ? make_float2(q.y, q.w) : make_float2(q.x, q.z);
}

// ---------------------------------------------------------------------------
// main RNN kernel. One wave per batch; lane owns rows (lane, lane+64).
// ---------------------------------------------------------------------------
__global__ __launch_bounds__(128) void rnn_kernel(const float* __restrict__ input,
                                                  const float* __restrict__ target,
                                                  const float* __restrict__ returns,
                                                  const float* __restrict__ cswg,
                                                  const float* __restrict__ vdg,
                                                  const float* __restrict__ absbg,
                                                  float* __restrict__ out) {
    __shared__ float csh[D * D];       // 64 KB quads
    __shared__ float s_sh[2][2 * 64];  // per-wave interleaved (s_lo, s_hi)
    __shared__ float ae_sh[2 * 64];    // interleaved (aeps_lo, aeps_hi)

    const int tid = threadIdx.x;
    const int w = tid >> 6;
    const int lane = tid & 63;
    const int b = blockIdx.x * 2 + w;
    const int rlo = lane, rhi = lane + 64;

    // cooperative linear copy of csw -> LDS (b128)
    {
        const float4* src = (const float4*)cswg;
        float4* dst = (float4*)csh;
#pragma unroll
        for (int c = 0; c < 32; ++c) dst[c * 128 + tid] = src[c * 128 + tid];
    }

    const float tgt_lo = target[rlo], tgt_hi = target[rhi];
    const float a_lo = absbg[rlo], a_hi = absbg[rhi];
    const float aeps_lo = a_lo + EPSF, aeps_hi = a_hi + EPSF;
    const float vd_lo = vdg[rlo], vd_hi = vdg[rhi];
    const float rvd_lo = 1.0f / vd_lo, rvd_hi = 1.0f / vd_hi;

    if (w == 0) *(float2*)&ae_sh[2 * lane] = make_float2(aeps_lo, aeps_hi);
    __syncthreads();

    // matvec base pointers: quad row j2 read at qb[j2&7] + j2*1024 bytes
    const char* qb[8];
#pragma unroll
    for (int c = 0; c < 8; ++c) qb[c] = (const char*)csh + 16 * (lane ^ c);

    float h_lo = input[rlo * T * B + b];
    float h_hi = input[rhi * T * B + b];
    out[rlo * T * B + b] = h_lo;
    out[rhi * T * B + b] = h_hi;

    float r_lo = returns[rlo * T * B + b];
    float r_hi = returns[rhi * T * B + b];

    for (int t = 1; t < T; ++t) {
        // ---- adj = h*(1+r)/(1 + sum(h*r)) ----
        float num_lo = h_lo * (1.0f + r_lo);
        float num_hi = h_hi * (1.0f + r_hi);
        float p = h_lo * r_lo + h_hi * r_hi;
#pragma unroll
        for (int off = 32; off; off >>= 1) p += __shfl_xor(p, off);
        float den = 1.0f + p;
        float adj_lo = num_lo / den;
        float adj_hi = num_hi / den;

        if (t < T - 1) {
            r_lo = returns[rlo * T * B + t * B + b];
            r_hi = returns[rhi * T * B + t * B + b];
        }

        const float x_lo = adj_lo - tgt_lo;
        const float x_hi = adj_hi - tgt_hi;

        // ---- s = v @ (adj - pi_bar): 64 ds_read_b128, imm offsets ----
        float a0 = 0, a1 = 0, b0 = 0, b1 = 0;
#pragma unroll
        for (int j2 = 0; j2 < 64; ++j2) {
            float4 q = *(const float4*)(qb[j2 & 7] + j2 * 1024);
            float x0, x1;
            if (j2 < 32) {
                x0 = lane_bcast(x_lo, 2 * j2);
                x1 = lane_bcast(x_lo, 2 * j2 + 1);
            } else {
                x0 = lane_bcast(x_hi, 2 * j2 - 64);
                x1 = lane_bcast(x_hi, 2 * j2 - 63);
            }
            a0 = fmaf(q.x, x0, a0);
            a1 = fmaf(q.y, x1, a1);
            b0 = fmaf(q.z, x0, b0);
            b1 = fmaf(q.w, x1, b1);
        }
        float s_lo = a0 + a1;
        float s_hi = b0 + b1;

        h_lo = adj_lo;
        h_hi = adj_hi;

        uint64_t mlo = __ballot(fabsf(s_lo) > a_lo);
        uint64_t mhi = __ballot(fabsf(s_hi) > a_hi);

        if ((mlo | mhi) != 0ull) {
            // per-lane candidate deltas from ORIGINAL s (reference semantics)
            float dl = 0.0f, dh = 0.0f;
            if (s_lo > a_lo) dl = (a_lo - s_lo) / vd_lo;
            else if (s_lo < -a_lo) dl = (-a_lo - s_lo) / vd_lo;
            if (s_hi > a_hi) dh = (a_hi - s_hi) / vd_hi;
            else if (s_hi < -a_hi) dh = (-a_hi - s_hi) / vd_hi;

            int V = __popcll(mlo) + __popcll(mhi);
            bool judge = false;

            int jn[8];
            float djs[8], clo_q[8], chi_q[8];
#pragma unroll
            for (int q = 0; q < 8; ++q) { jn[q] = -1; djs[q] = 0; clo_q[q] = 0; chi_q[q] = 0; }

            if (V <= 8) {
                // q0 shortcut (V<128 so a zero-delta candidate exists)
                bool in_lo = (s_lo < aeps_lo) && (s_lo > -aeps_lo);
                bool in_hi = (s_hi < aeps_hi) && (s_hi > -aeps_hi);
                judge = (__ballot(in_lo && in_hi) == ~0ull);
                // gather all violating candidates (columns reused by sweep)
                {
                    uint64_t tml = mlo, tmh = mhi;
#pragma unroll
                    for (int q = 0; q < 8; ++q) {
                        int j = -1;
                        if (tml) {
                            j = (int)__ffsll((unsigned long long)tml) - 1;
                            tml &= tml - 1;
                        } else if (tmh) {
                            j = 64 + (int)__ffsll((unsigned long long)tmh) - 1;
                            tmh &= tmh - 1;
                        }
                        jn[q] = j;
                        if (j >= 0) {
                            djs[q] = lane_bcast((j < 64) ? dl : dh, j & 63);
                            float2 cp = colq(csh, j, lane);
                            clo_q[q] = cp.x;
                            chi_q[q] = cp.y;
                        }
                    }
                }
                if (!judge) {
                    // batch test: pack 8 pass-bits, AND-reduce across wave
                    unsigned mbits = 0;
#pragma unroll
                    for (int q = 0; q < 8; ++q) {
                        if (jn[q] >= 0) {
                            float n_lo = fmaf(clo_q[q], djs[q], s_lo);
                            float n_hi = fmaf(chi_q[q], djs[q], s_hi);
                            bool ok = (n_lo < aeps_lo) && (n_lo > -aeps_lo) &&
                                      (n_hi < aeps_hi) && (n_hi > -aeps_hi);
                            mbits |= ok ? (1u << q) : 0u;
                        }
                    }
#pragma unroll
                    for (int off = 1; off < 64; off <<= 1)
                        mbits &= (unsigned)__shfl_xor((int)mbits, off);
                    judge = (mbits != 0u);
                }
            } else {
                // ---- parallel judge: lane tests candidates j=lane, lane+64 ----
                *(float2*)&s_sh[w][2 * lane] = make_float2(s_lo, s_hi);
                const int par = lane & 1;
                const int j2s = lane >> 1;
                const float* jbase = csh + 4 * (j2s * 64);
                const int jx = j2s & 7;
                float m1 = -1.0f, m2 = -1.0f;
#pragma unroll
                for (int c = 0; c < 64; ++c) {
                    const float* pr = jbase + 4 * (c ^ jx);
                    float4 q1 = *(const float4*)pr;            // cols 2*j2s, 2*j2s+1
                    float4 q2 = *(const float4*)(pr + 8192);   // cols +64
                    float c1lo = par ? q1.y : q1.x;   // v[c][lane]
                    float c1hi = par ? q1.w : q1.z;   // v[c+64][lane]
                    float c2lo = par ? q2.y : q2.x;   // v[c][lane+64]
                    float c2hi = par ? q2.w : q2.z;   // v[c+64][lane+64]
                    float2 sv = *(const float2*)&s_sh[w][2 * c];
                    float2 ae = *(const float2*)&ae_sh[2 * c];
                    m1 = fmaxf(m1, fabsf(fmaf(c1lo, dl, sv.x)) - ae.x);
                    m1 = fmaxf(m1, fabsf(fmaf(c1hi, dl, sv.y)) - ae.y);
                    m2 = fmaxf(m2, fabsf(fmaf(c2lo, dh, sv.x)) - ae.x);
                    m2 = fmaxf(m2, fabsf(fmaf(c2hi, dh, sv.y)) - ae.y);
                }
                judge = ((__ballot(m1 < 0.0f) | __ballot(m2 < 0.0f)) != 0ull);
            }

            if (judge) {
                // ---- Gauss-Seidel sweep (ascending j, violators only) ----
                uint64_t rem_lo = ~0ull, rem_hi = ~0ull;
                while (true) {
                    uint64_t m1b = __ballot(fabsf(s_lo) > a_lo) & rem_lo;
                    uint64_t m2b = __ballot(fabsf(s_hi) > a_hi) & rem_hi;
                    int j;
                    if (m1b) {
                        int jl = (int)__ffsll((unsigned long long)m1b) - 1;
                        j = jl;
                        rem_lo = (jl == 63) ? 0ull : (~0ull << (jl + 1));
                    } else if (m2b) {
                        int jh = (int)__ffsll((unsigned long long)m2b) - 1;
                        j = 64 + jh;
                        rem_lo = 0ull;
                        rem_hi = (jh == 63) ? 0ull : (~0ull << (jh + 1));
                    } else {
                        break;
                    }
                    float dl2 = (s_lo > a_lo) ? (a_lo - s_lo) * rvd_lo
                               : ((s_lo < -a_lo) ? (-a_lo - s_lo) * rvd_lo : 0.0f);
                    float dh2 = (s_hi > a_hi) ? (a_hi - s_hi) * rvd_hi
                               : ((s_hi < -a_hi) ? (-a_hi - s_hi) * rvd_hi : 0.0f);
                    float dj = lane_bcast((j < 64) ? dl2 : dh2, j & 63);
                    if (lane == (j & 63)) {
                        if (j < 64) h_lo += dj; else h_hi += dj;
                    }
                    // column: reuse probe prefetch if available
                    float clo = 0.0f, chi = 0.0f;
                    bool have = false;
#pragma unroll
                    for (int q = 0; q < 8; ++q)
                        if (jn[q] == j) { clo = clo_q[q]; chi = chi_q[q]; have = true; }
                    if (!have) {
                        float2 cp = colq(csh, j, lane);
                        clo = cp.x; chi = cp.y;
                    }
                    s_lo = fmaf(clo, dj, s_lo);
                    s_hi = fmaf(chi, dj, s_hi);
                }
            } else {
                // ---- bisection between pi_bar (s=0) and adj (s), s-space ----
                float hin_lo = tgt_lo, hin_hi = tgt_hi;
                float sin_lo = 0.0f, sin_hi = 0.0f;
                float hout_lo = h_lo, hout_hi = h_hi;
                float sout_lo = s_lo, sout_hi = s_hi;
                float hm_lo = 0.0f, hm_hi = 0.0f;
#pragma unroll
                for (int it = 0; it < 10; ++it) {
                    hm_lo = hin_lo + (hout_lo - hin_lo) * 0.5f;
                    hm_hi = hin_hi + (hout_hi - hin_hi) * 0.5f;
                    float sm_lo = sin_lo + (sout_lo - sin_lo) * 0.5f;
                    float sm_hi = sin_hi + (sout_hi - sin_hi) * 0.5f;
                    bool pl = (sm_lo <= aeps_lo) && (sm_lo >= -aeps_lo);
                    bool ph = (sm_hi <= aeps_hi) && (sm_hi >= -aeps_hi);
                    bool inside = (__ballot(pl && ph) == ~0ull);
                    if (inside) {
                        hin_lo = hm_lo; hin_hi = hm_hi;
                        sin_lo = sm_lo; sin_hi = sm_hi;
                    } else {
                        hout_lo = hm_lo; hout_hi = hm_hi;
                        sout_lo = sm_lo; sout_hi = sm_hi;
                    }
                }
                h_lo = hm_lo;
                h_hi = hm_hi;
            }
        }
        // else: no violators -> judge=1, sweep no-op, h = adj unchanged

        out[rlo * T * B + t * B + b] = h_lo;
        out[rhi * T * B + t * B + b] = h_hi;
    }

    out[D * T * B + rlo * B + b] = h_lo;
    out[D * T * B + rhi * B + b] = h_hi;
}

extern "C" void kernel_launch(void* const* d_in, const int* in_sizes, int n_in,
                              void* d_out, int out_size, void* d_ws, size_t ws_size,
                              hipStream_t stream) {
    const float* input   = (const float*)d_in[0];
    const float* target  = (const float*)d_in[1];
    const float* returns = (const float*)d_in[2];
    // d_in[3] = hidden (unused by the reference)
    const float* W = (const float*)d_in[4];
    const float* b = (const float*)d_in[5];
    float* out = (float*)d_out;

    float* csw  = (float*)d_ws;            // 16384 floats (quad layout)
    float* vd   = csw + D * D;             // 128 floats
    float* absb = vd + D;                  // 128 floats

    prep_kernel<<<D, 64, 0, stream>>>(W, b, csw, vd, absb);
    rnn_kernel<<<B / 2, 128, 0, stream>>>(input, target, returns, csw, vd, absb, out);
}